// Round 6
// baseline (304.142 us; speedup 1.0000x reference)
//
#include <hip/hip_runtime.h>
#include <hip/hip_bf16.h>

// corr[b,h,w] = (1/HW) * sum_c fmap1[b,c,h,w] * sum_{k,l} fmap2[b,c,k,l]
// B=8, C=256, H=W=96, HW=9216. Output [B,1,H,W] f32 (73728 elements).
//
// Single fused kernel; manual grid-wide sync via device-scope semaphore.
// (hipLaunchCooperativeKernel fails in this harness even uncaptured — R3.)
// R4 bug fixed: each 1024-float subjob now fully covered (4 float4/lane).

#define B_ 8
#define C_ 256
#define HW_ 9216            // 96*96
#define NPLANE (B_ * C_)    // 2048 planes of 9216 floats
#define GRID_ 576           // 8 b * 9 hwblk * 8 cblk ; 2.25 blocks/CU

// ---------------------------------------------------------------------------
// Phase A: plane sums of f2. 18432 subjobs = (plane 0..2047, ninth 0..8),
//          1024 contiguous floats each. One WAVE per subjob: 4 coalesced
//          float4 rounds (64 lanes * 4 * 4 = 1024 floats), wave-reduce,
//          lane0 atomicAdd into m2sum[plane] (9 adds/plane, pre-zeroed).
//          32 subjobs/block (8 per wave). Blocks 0..71 also zero d_out.
// Sync:    release-increment sem; t0 acquire-spins until sem == GRID_.
//          __launch_bounds__(256,4) -> >=4 blocks/CU co-resident capacity
//          (1024 >= 576, 1.8x margin) -> spin cannot deadlock. Bounded spin
//          converts any surprise into a wrong answer, not a hang.
// Phase B: block (b, hwblk, cblk) contracts 32 channels over 1024 positions
//          (float4/thread), scales by 1/HW, atomicAdds into d_out (8-way
//          contention per address). m2sum read via AGENT-scope atomic loads
//          -> immune to per-XCD L2 staleness.
// ---------------------------------------------------------------------------
__global__ __launch_bounds__(256, 4) void fused_kernel(const float* __restrict__ f1,
                                                       const float* __restrict__ f2,
                                                       float* __restrict__ m2sum,
                                                       unsigned int* __restrict__ sem,
                                                       float* __restrict__ out) {
    const int t    = threadIdx.x;
    const int bid  = blockIdx.x;
    const int wave = t >> 6;
    const int lane = t & 63;

    // ---- phase A ----
    if (bid < 72) {
        ((float4*)out)[bid * 256 + t] = make_float4(0.f, 0.f, 0.f, 0.f);
    }

#pragma unroll 4
    for (int it = 0; it < 8; ++it) {
        const int s   = bid * 32 + it * 4 + wave;    // subjob 0..18431
        const int pp  = s / 9;                       // plane 0..2047
        const int sub = s - pp * 9;                  // ninth 0..8
        const float4* base = (const float4*)(f2 + (size_t)pp * HW_ + sub * 1024);
        const float4 a = base[lane];
        const float4 b = base[lane + 64];
        const float4 c = base[lane + 128];
        const float4 d = base[lane + 192];
        float r = ((a.x + a.y) + (a.z + a.w)) + ((b.x + b.y) + (b.z + b.w))
                + ((c.x + c.y) + (c.z + c.w)) + ((d.x + d.y) + (d.z + d.w));
#pragma unroll
        for (int off = 32; off; off >>= 1)
            r += __shfl_down(r, off, 64);
        if (lane == 0) atomicAdd(&m2sum[pp], r);
    }

    // ---- grid-wide sync (release -> spin-acquire) ----
    __threadfence();        // drain stores/atomics to agent scope
    __syncthreads();        // whole block has fenced
    if (t == 0) {
        __hip_atomic_fetch_add(sem, 1u, __ATOMIC_RELEASE, __HIP_MEMORY_SCOPE_AGENT);
        unsigned int spins = 0;
        while (__hip_atomic_load(sem, __ATOMIC_ACQUIRE, __HIP_MEMORY_SCOPE_AGENT) < GRID_) {
            __builtin_amdgcn_s_sleep(2);
            if (++spins > (1u << 22)) break;     // should never trigger
        }
    }
    __syncthreads();

    // ---- phase B ----
    const int b     = bid / 72;            // 72 = 9 hwblk * 8 cblk
    const int rem   = bid % 72;
    const int hwblk = rem / 8;             // 0..8
    const int cblk  = rem % 8;             // 0..7
    const int c0    = cblk * 32;
    const int pos   = hwblk * 1024 + t * 4;

    __shared__ float sm2[32];
    if (t < 32)
        sm2[t] = __hip_atomic_load(&m2sum[b * C_ + c0 + t],
                                   __ATOMIC_RELAXED, __HIP_MEMORY_SCOPE_AGENT);
    __syncthreads();

    const float* f1base = f1 + ((size_t)(b * C_ + c0)) * HW_ + pos;
    float4 acc = {0.f, 0.f, 0.f, 0.f};
#pragma unroll
    for (int i = 0; i < 32; ++i) {
        const float  s = sm2[i];
        const float4 w = *(const float4*)(f1base + (size_t)i * HW_);
        acc.x += w.x * s;
        acc.y += w.y * s;
        acc.z += w.z * s;
        acc.w += w.w * s;
    }

    const float inv = 1.0f / (float)HW_;
    float* o = out + (size_t)b * HW_ + pos;
    atomicAdd(o + 0, acc.x * inv);
    atomicAdd(o + 1, acc.y * inv);
    atomicAdd(o + 2, acc.z * inv);
    atomicAdd(o + 3, acc.w * inv);
}

extern "C" void kernel_launch(void* const* d_in, const int* in_sizes, int n_in,
                              void* d_out, int out_size, void* d_ws, size_t ws_size,
                              hipStream_t stream) {
    const float* f1 = (const float*)d_in[0];
    const float* f2 = (const float*)d_in[1];
    float* out = (float*)d_out;
    float* m2sum = (float*)d_ws;                          // 2048 floats
    unsigned int* sem = (unsigned int*)(m2sum + NPLANE);  // 1 uint

    // ws is poisoned 0xAA before every timed launch -> zero m2sum + sem.
    hipMemsetAsync(d_ws, 0, (NPLANE + 4) * sizeof(float), stream);

    fused_kernel<<<GRID_, 256, 0, stream>>>(f1, f2, m2sum, sem, out);
}

// Round 7
// 269.038 us; speedup vs baseline: 1.1305x; 1.1305x over previous
//
#include <hip/hip_runtime.h>
#include <hip/hip_bf16.h>

// corr[b,h,w] = sum_c fmap1[b,c,h,w] * mean_{k,l} fmap2[b,c,k,l]
// B=8, C=256, H=W=96, HW=9216. Output [B,1,H,W] f32 (73728 elements).
//
// ONE dispatch, no memsets. Manual grid sync with MAGIC flags:
//  - writers: __threadfence (release) then relaxed-store flag = MAGIC
//  - pollers: RELAXED agent loads (no buffer_inv per iteration — R6's
//    ACQUIRE-spin invalidated L1/L2 continuously and ran 194 us)
//  - m2 read back with relaxed AGENT loads (coherence point; R6-proven).
// Phase A has no atomics (one wave sums one full plane) -> ws needs no
// pre-zero -> no memset dispatch (every dispatch costs ~45 us here).

#define B_ 8
#define C_ 256
#define HW_ 9216            // 96*96
#define NPLANE (B_ * C_)    // 2048
#define GRID_ 576           // 8 b * 9 hwblk * 8 cblk
#define MAGIC_ 0xC0FFEE01u  // != 0xAAAAAAAA poison, != 0

// __launch_bounds__(256,4): 4 waves/SIMD -> VGPR<=128, 4 blocks/CU ->
// 1024 co-resident capacity >= 576 blocks: the spin cannot deadlock.
__global__ __launch_bounds__(256, 4) void fused_kernel(const float* __restrict__ f1,
                                                       const float* __restrict__ f2,
                                                       float* __restrict__ m2,
                                                       unsigned int* __restrict__ flags,
                                                       float* __restrict__ out) {
    const int t    = threadIdx.x;
    const int bid  = blockIdx.x;
    const int wave = t >> 6;
    const int lane = t & 63;

    // ---- phase A ----
    // d_out zeroing: blocks 504..575 (mostly idle in plane summing).
    if (bid >= 504) {
        ((float4*)out)[(bid - 504) * 256 + t] = make_float4(0.f, 0.f, 0.f, 0.f);
    }

    // One wave per plane: 9216 floats = 36 float4/lane, 3 rounds of 12 in flight.
    const int gw = bid * 4 + wave;            // 0..2303; planes 0..2047
    if (gw < NPLANE) {
        const float4* base = (const float4*)(f2 + (size_t)gw * HW_);
        float a0 = 0.f, a1 = 0.f, a2 = 0.f, a3 = 0.f;
#pragma unroll
        for (int r = 0; r < 3; ++r) {
            float4 v[12];
#pragma unroll
            for (int i = 0; i < 12; ++i) v[i] = base[lane + (r * 12 + i) * 64];
#pragma unroll
            for (int i = 0; i < 12; i += 4) {
                a0 += (v[i+0].x + v[i+0].y) + (v[i+0].z + v[i+0].w);
                a1 += (v[i+1].x + v[i+1].y) + (v[i+1].z + v[i+1].w);
                a2 += (v[i+2].x + v[i+2].y) + (v[i+2].z + v[i+2].w);
                a3 += (v[i+3].x + v[i+3].y) + (v[i+3].z + v[i+3].w);
            }
        }
        float s = (a0 + a1) + (a2 + a3);
#pragma unroll
        for (int off = 32; off; off >>= 1) s += __shfl_down(s, off, 64);
        if (lane == 0) m2[gw] = s * (1.0f / (float)HW_);   // mean, pre-scaled
    }

    // ---- grid-wide sync: release flag, relaxed poll ----
    __threadfence();        // wbl2: m2 + out-zeros reach coherence point
    __syncthreads();        // whole block has fenced
    if (t == 0)
        __hip_atomic_store(&flags[bid], MAGIC_, __ATOMIC_RELAXED,
                           __HIP_MEMORY_SCOPE_AGENT);
    if (wave == 0) {        // wave 0 polls all 576 flags, 9 per lane
        unsigned spins = 0;
        bool alldone = false;
        while (!alldone && ++spins < (1u << 20)) {
            bool mine = true;
#pragma unroll
            for (int j = 0; j < 9; ++j)
                mine &= (__hip_atomic_load(&flags[lane * 9 + j], __ATOMIC_RELAXED,
                                           __HIP_MEMORY_SCOPE_AGENT) == MAGIC_);
            alldone = __all(mine);
            if (!alldone) __builtin_amdgcn_s_sleep(4);
        }
    }
    __syncthreads();

    // ---- phase B ----
    const int b     = bid / 72;            // 72 = 9 hwblk * 8 cblk
    const int rem   = bid % 72;
    const int hwblk = rem / 8;             // 0..8
    const int cblk  = rem % 8;             // 0..7
    const int c0    = cblk * 32;
    const int pos   = hwblk * 1024 + t * 4;

    __shared__ float sm2[32];
    if (t < 32)
        sm2[t] = __hip_atomic_load(&m2[b * C_ + c0 + t],
                                   __ATOMIC_RELAXED, __HIP_MEMORY_SCOPE_AGENT);
    __syncthreads();

    const float* f1b = f1 + ((size_t)(b * C_ + c0)) * HW_ + pos;
    float4 w[8];
#pragma unroll
    for (int i = 0; i < 8; ++i) w[i] = *(const float4*)(f1b + (size_t)i * HW_);
    float4 acc = make_float4(0.f, 0.f, 0.f, 0.f);
#pragma unroll
    for (int r = 0; r < 3; ++r) {
#pragma unroll
        for (int i = 0; i < 8; ++i) {
            const float4 x = w[i];
            const float  s = sm2[r * 8 + i];
            w[i] = *(const float4*)(f1b + (size_t)((r + 1) * 8 + i) * HW_);
            acc.x += x.x * s; acc.y += x.y * s;
            acc.z += x.z * s; acc.w += x.w * s;
        }
    }
#pragma unroll
    for (int i = 0; i < 8; ++i) {
        const float s = sm2[24 + i];
        acc.x += w[i].x * s; acc.y += w[i].y * s;
        acc.z += w[i].z * s; acc.w += w[i].w * s;
    }

    float* o = out + (size_t)b * HW_ + pos;
    atomicAdd(o + 0, acc.x);
    atomicAdd(o + 1, acc.y);
    atomicAdd(o + 2, acc.z);
    atomicAdd(o + 3, acc.w);
}

extern "C" void kernel_launch(void* const* d_in, const int* in_sizes, int n_in,
                              void* d_out, int out_size, void* d_ws, size_t ws_size,
                              hipStream_t stream) {
    const float* f1 = (const float*)d_in[0];
    const float* f2 = (const float*)d_in[1];
    float* out = (float*)d_out;
    float* m2  = (float*)d_ws;                            // 2048 floats
    unsigned int* flags = (unsigned int*)(m2 + NPLANE);   // 576 uints
    // flags arrive poisoned 0xAAAAAAAA (!= MAGIC) every launch -> no memset.

    fused_kernel<<<GRID_, 256, 0, stream>>>(f1, f2, m2, flags, out);
}

// Round 8
// 169.205 us; speedup vs baseline: 1.7975x; 1.5900x over previous
//
#include <hip/hip_runtime.h>
#include <hip/hip_bf16.h>

// corr[b,h,w] = sum_c fmap1[b,c,h,w] * mean_{k,l} fmap2[b,c,k,l]
// B=8, C=256, H=W=96, HW=9216. Output [B,1,H,W] f32 (73728 elements).
//
// Two plain kernels (fused + manual grid-sync was 4x slower than its
// component sum in R6/R7 — sync machinery poisons the memory path).
// No atomics on the output, no memsets: every output element is stored
// exactly once; m2 is fully written by kernel 1 (stream-ordered).

#define B_ 8
#define C_ 256
#define HW_ 9216            // 96*96
#define NPLANE (B_ * C_)    // 2048

// ---------------- Kernel 1: m2[b,c] = (1/HW) * sum_hw f2[b,c,:,:] ----------
// One block per (b,c) plane. 256 threads x 9 float4 = 9216 floats, all 9
// loads in flight, wave shfl-reduce, LDS combine. 2048 blocks = 8/CU.
__global__ __launch_bounds__(256) void mean2_kernel(const float* __restrict__ f2,
                                                    float* __restrict__ m2) {
    const int bc = blockIdx.x;                       // 0..2047
    const int t  = threadIdx.x;
    const float4* p = (const float4*)(f2 + (size_t)bc * HW_);

    float4 v[9];
#pragma unroll
    for (int k = 0; k < 9; ++k) v[k] = p[t + k * 256];   // 9 loads in flight
    float s = 0.f;
#pragma unroll
    for (int k = 0; k < 9; ++k) s += (v[k].x + v[k].y) + (v[k].z + v[k].w);

#pragma unroll
    for (int off = 32; off; off >>= 1) s += __shfl_down(s, off, 64);

    __shared__ float ws[4];
    if ((t & 63) == 0) ws[t >> 6] = s;
    __syncthreads();
    if (t == 0) m2[bc] = ((ws[0] + ws[1]) + (ws[2] + ws[3])) * (1.0f / (float)HW_);
}

// ---------------- Kernel 2: corr[b,pos] = sum_c f1[b,c,pos] * m2[b,c] ------
// 1152 blocks = 8 b x 144 chunks of 64 positions. 256 threads/block:
// wave w (0..3) covers channels [64w, 64w+64), lane = position offset.
// Each lane: 64 independent coalesced dword loads (256B/instr), FMA with
// LDS-broadcast m2. 4 partials combined via LDS; 64 lanes store the chunk.
// Atomic-free, zero-init-free. 4.5 blocks/CU = 18 waves/CU.
__global__ __launch_bounds__(256) void corr_kernel(const float* __restrict__ f1,
                                                   const float* __restrict__ m2,
                                                   float* __restrict__ out) {
    const int bid   = blockIdx.x;          // 0..1151
    const int b     = bid / 144;
    const int chunk = bid % 144;           // 64-position chunk
    const int t     = threadIdx.x;
    const int w     = t >> 6;              // wave 0..3 -> channel quarter
    const int lane  = t & 63;
    const int pos   = chunk * 64 + lane;

    __shared__ float sm2[C_];
    sm2[t] = m2[b * C_ + t];               // coalesced, 256 floats
    __syncthreads();

    const float* base = f1 + ((size_t)(b * C_ + w * 64)) * HW_ + pos;
    float acc = 0.f;
#pragma unroll 8
    for (int i = 0; i < 64; ++i) {
        acc += sm2[w * 64 + i] * base[(size_t)i * HW_];  // LDS broadcast x coalesced load
    }

    __shared__ float part[256];
    part[t] = acc;
    __syncthreads();
    if (t < 64) {
        const float r = (part[t] + part[t + 64]) + (part[t + 128] + part[t + 192]);
        out[(size_t)b * HW_ + chunk * 64 + t] = r;       // stored exactly once
    }
}

extern "C" void kernel_launch(void* const* d_in, const int* in_sizes, int n_in,
                              void* d_out, int out_size, void* d_ws, size_t ws_size,
                              hipStream_t stream) {
    const float* f1 = (const float*)d_in[0];
    const float* f2 = (const float*)d_in[1];
    float* out = (float*)d_out;
    float* m2  = (float*)d_ws;      // 2048 floats = 8 KB

    mean2_kernel<<<NPLANE, 256, 0, stream>>>(f2, m2);
    corr_kernel<<<1152, 256, 0, stream>>>(f1, m2, out);
}